// Round 7
// baseline (520.937 us; speedup 1.0000x reference)
//
#include <hip/hip_runtime.h>

#define D       128
#define NNODES  50000
#define NEDGES  600000
#define TE      64           // edges per block (9375 blocks, no tail)
#define TN      64           // nodes per block
#define BLK     256
#define LN_EPS  1e-5f

typedef float  fx4    __attribute__((ext_vector_type(4)));
typedef float  f32x4  __attribute__((ext_vector_type(4)));
typedef __bf16 bf16x4 __attribute__((ext_vector_type(4)));
typedef __bf16 bf16x8 __attribute__((ext_vector_type(8)));

// ---- d_ws layout ----
// Fragment-major weights (bf16): frag[kstep][nf][lane(64)][8], 512 bf16/frag.
#define EW1F_OFF 0                         // K=384: 12 ksteps * 8 nf
#define EW2F_OFF (128 * 384)               // K=128:  4 ksteps * 8 nf
#define NW1F_OFF (EW2F_OFF + 128 * 128)    // K=256:  8 ksteps * 8 nf
#define NW2F_OFF (NW1F_OFF + 128 * 256)    // K=128
#define WS_ELEMS (NW2F_OFF + 128 * 128)    // 114688 bf16
#define W_BYTES  (WS_ELEMS * 2)            // 229376 B
// f32 precompute arrays (byte offsets)
#define PD_OFF      ((size_t)W_BYTES)
#define PS_OFF      (PD_OFF + (size_t)NNODES * D * 4)
#define WS_NEED_PRE (PS_OFF + (size_t)NNODES * D * 4)   // ~51.7 MB

__device__ __forceinline__ float silu_f(float z) {
    return z * (1.0f / (1.0f + __expf(-z)));
}

// ---------------------------------------------------------------------------
// Weight prep: f32 [K][128] -> bf16 fragment-major.
// frag f = ks*8+nf ; lane l ; elem j  maps to  n = nf*16+(l&15),
// k = ks*32 + (l>>4)*8 + j.  Stored at  base + f*512 + l*8 + j.
// ---------------------------------------------------------------------------
__global__ __launch_bounds__(256) void prep_weights(
    const float* __restrict__ eW1, const float* __restrict__ eW2,
    const float* __restrict__ nW1, const float* __restrict__ nW2,
    __bf16* __restrict__ ws)
{
    int idx = blockIdx.x * 256 + threadIdx.x;
    if (idx >= WS_ELEMS) return;
    const float* src;
    int local;
    if (idx < EW2F_OFF)      { src = eW1; local = idx; }
    else if (idx < NW1F_OFF) { src = eW2; local = idx - EW2F_OFF; }
    else if (idx < NW2F_OFF) { src = nW1; local = idx - NW1F_OFF; }
    else                     { src = nW2; local = idx - NW2F_OFF; }
    const int f   = local >> 9;
    const int rem = local & 511;
    const int l   = rem >> 3;
    const int j   = rem & 7;
    const int ks  = f >> 3;
    const int nf  = f & 7;
    const int n   = (nf << 4) + (l & 15);
    const int k   = (ks << 5) + ((l >> 4) << 3) + j;
    ws[idx] = (__bf16)src[(size_t)k * D + n];
}

// ---------------------------------------------------------------------------
// Per-node precompute: Pd[n] = x[n] @ W1[0:128] + b1 ; Ps[n] = x[n] @ W1[128:256]
// 64 nodes/block, 4 waves x 16 rows, wave-private staging (no barriers).
// ---------------------------------------------------------------------------
__global__ __launch_bounds__(256) void pre_nodes(
    const float* __restrict__ x,
    const __bf16* __restrict__ W1f,   // edge W1 fragment-major (12 ksteps)
    const float* __restrict__ b1,
    float* __restrict__ Pd,
    float* __restrict__ Ps)
{
    __shared__ __bf16 xt[TN][136];

    const int tid = threadIdx.x;
    const int r0g = blockIdx.x * TN;
    const int lane  = tid & 63;
    const int wid   = tid >> 6;
    const int wrow0 = wid << 4;
    const int c16   = lane & 15;
    const int kq    = lane >> 4;
    const int ks8   = kq << 3;
    const int lo8   = lane << 3;

    // wave-private stage: 16 rows x 32 fx4 chunks
    #pragma unroll
    for (int pass = 0; pass < 8; ++pass) {
        const int row = wrow0 + (pass << 1) + (lane >> 5);
        const int gr  = r0g + row;
        const int c4  = (lane & 31) << 2;
        fx4 v = {0.f, 0.f, 0.f, 0.f};
        if (gr < NNODES) v = *(const fx4*)&x[(size_t)gr * D + c4];
        bf16x4 h;
        #pragma unroll
        for (int j = 0; j < 4; ++j) h[j] = (__bf16)v[j];
        *(bf16x4*)&xt[row][c4] = h;
    }

    f32x4 acc_d[8], acc_s[8];
    #pragma unroll
    for (int nf = 0; nf < 8; ++nf) {
        acc_d[nf] = (f32x4){0.f, 0.f, 0.f, 0.f};
        acc_s[nf] = (f32x4){0.f, 0.f, 0.f, 0.f};
    }

    #pragma unroll
    for (int ks = 0; ks < 4; ++ks) {
        bf16x8 a = *(const bf16x8*)&xt[wrow0 + c16][(ks << 5) + ks8];
        const __bf16* wpd = W1f + ((size_t)(ks << 3) << 9) + lo8;
        const __bf16* wps = W1f + ((size_t)((4 + ks) << 3) << 9) + lo8;
        #pragma unroll
        for (int nf = 0; nf < 8; ++nf) {
            bf16x8 bd = *(const bf16x8*)(wpd + (nf << 9));
            bf16x8 bs = *(const bf16x8*)(wps + (nf << 9));
            acc_d[nf] = __builtin_amdgcn_mfma_f32_16x16x32_bf16(a, bd, acc_d[nf], 0, 0, 0);
            acc_s[nf] = __builtin_amdgcn_mfma_f32_16x16x32_bf16(a, bs, acc_s[nf], 0, 0, 0);
        }
    }

    #pragma unroll
    for (int nf = 0; nf < 8; ++nf) {
        const int col = nf * 16 + c16;
        const float bb = b1[col];
        #pragma unroll
        for (int r = 0; r < 4; ++r) {
            const int row = r0g + wrow0 + kq * 4 + r;
            if (row < NNODES) {
                Pd[(size_t)row * D + col] = acc_d[nf][r] + bb;
                Ps[(size_t)row * D + col] = acc_s[nf][r];
            }
        }
    }
}

// ---------------------------------------------------------------------------
// Edge kernel (precompute path): 64 edges/block, 4 waves x 16 rows,
// ZERO barriers (all LDS traffic is wave-private rows).
//   sum = Pd[dst] + Ps[src]          (gather, elementwise)
//   h1  = silu(edge_attr @ W1e + sum)   (MFMA K=128)
//   e_new = LN(h1 @ W2 + b2)*g + b      (MFMA K=128)
// ---------------------------------------------------------------------------
__global__ __launch_bounds__(BLK, 5) void edge_kernel_pre(
    const float* __restrict__ edge_attr,
    const int*   __restrict__ edge_index,
    const float* __restrict__ Pd,
    const float* __restrict__ Ps,
    const __bf16* __restrict__ W1f,   // full edge-W1 frags; W1e = ksteps 8..11
    const __bf16* __restrict__ W2f,
    const float* __restrict__ b2,
    const float* __restrict__ lng, const float* __restrict__ lnb,
    float* __restrict__ edges_out,
    float* __restrict__ agg)
{
    __shared__ __bf16 sum_t[TE][136];   // sum, then h1 in place

    const int tid = threadIdx.x;
    const int e0g = blockIdx.x * TE;
    const int lane  = tid & 63;
    const int wid   = tid >> 6;
    const int wrow0 = wid << 4;
    const int c16   = lane & 15;
    const int kq    = lane >> 4;
    const int ks8   = kq << 3;
    const int lo8   = lane << 3;

    // ---- gather Pd[dst]+Ps[src] into LDS (wave-private rows) ----
    #pragma unroll
    for (int pass = 0; pass < 8; ++pass) {
        const int row = wrow0 + (pass << 1) + (lane >> 5);
        const int ge  = e0g + row;
        const int dn  = edge_index[NEDGES + ge];   // dst (i)
        const int sn  = edge_index[ge];            // src (j)
        const int c4  = (lane & 31) << 2;
        fx4 a = *(const fx4*)&Pd[(size_t)dn * D + c4];
        fx4 b = *(const fx4*)&Ps[(size_t)sn * D + c4];
        bf16x4 h;
        #pragma unroll
        for (int j = 0; j < 4; ++j) h[j] = (__bf16)(a[j] + b[j]);
        *(bf16x4*)&sum_t[row][c4] = h;
    }

    // ---- edge_attr A-fragments straight from global ----
    bf16x8 aE[4];
    {
        const float* ep = edge_attr + (size_t)(e0g + wrow0 + c16) * D + ks8;
        #pragma unroll
        for (int ks2 = 0; ks2 < 4; ++ks2) {
            fx4 v0 = *(const fx4*)(ep + (ks2 << 5));
            fx4 v1 = *(const fx4*)(ep + (ks2 << 5) + 4);
            bf16x8 a;
            #pragma unroll
            for (int j = 0; j < 4; ++j) { a[j] = (__bf16)v0[j]; a[j + 4] = (__bf16)v1[j]; }
            aE[ks2] = a;
        }
    }

    // ---- GEMM1e: edge_attr @ W1e (ksteps 8..11 of W1f) ----
    f32x4 acc[8];
    #pragma unroll
    for (int nf = 0; nf < 8; ++nf) acc[nf] = (f32x4){0.f, 0.f, 0.f, 0.f};

    #pragma unroll
    for (int ks2 = 0; ks2 < 4; ++ks2) {
        const __bf16* wp = W1f + ((size_t)((8 + ks2) << 3) << 9) + lo8;
        #pragma unroll
        for (int nf = 0; nf < 8; ++nf) {
            bf16x8 b = *(const bf16x8*)(wp + (nf << 9));
            acc[nf] = __builtin_amdgcn_mfma_f32_16x16x32_bf16(aE[ks2], b, acc[nf], 0, 0, 0);
        }
    }

    // ---- h1 = silu(acc + sum), written in place (wave-private rows) ----
    #pragma unroll
    for (int nf = 0; nf < 8; ++nf) {
        #pragma unroll
        for (int r = 0; r < 4; ++r) {
            const int row = wrow0 + kq * 4 + r;
            const int col = nf * 16 + c16;
            float z = acc[nf][r] + (float)sum_t[row][col];
            sum_t[row][col] = (__bf16)silu_f(z);
        }
    }

    // ---- GEMM2: h1 @ W2 ----
    f32x4 acc2[8];
    #pragma unroll
    for (int nf = 0; nf < 8; ++nf) acc2[nf] = (f32x4){0.f, 0.f, 0.f, 0.f};

    #pragma unroll
    for (int ks = 0; ks < 4; ++ks) {
        bf16x8 a = *(const bf16x8*)&sum_t[wrow0 + c16][(ks << 5) + ks8];
        const __bf16* wp = W2f + ((size_t)(ks << 3) << 9) + lo8;
        #pragma unroll
        for (int nf = 0; nf < 8; ++nf) {
            bf16x8 b = *(const bf16x8*)(wp + (nf << 9));
            acc2[nf] = __builtin_amdgcn_mfma_f32_16x16x32_bf16(a, b, acc2[nf], 0, 0, 0);
        }
    }

    // ---- bias + LayerNorm + store + scatter-add ----
    float b2v[8], gv[8], bvv[8];
    #pragma unroll
    for (int nf = 0; nf < 8; ++nf) {
        b2v[nf] = b2[nf * 16 + c16];
        gv[nf]  = lng[nf * 16 + c16];
        bvv[nf] = lnb[nf * 16 + c16];
    }

    float s[4] = {0.f, 0.f, 0.f, 0.f}, q[4] = {0.f, 0.f, 0.f, 0.f};
    #pragma unroll
    for (int nf = 0; nf < 8; ++nf)
        #pragma unroll
        for (int r = 0; r < 4; ++r) {
            float zz = acc2[nf][r] + b2v[nf];
            acc2[nf][r] = zz;
            s[r] += zz;
            q[r] += zz * zz;
        }
    #pragma unroll
    for (int m = 1; m <= 8; m <<= 1)
        #pragma unroll
        for (int r = 0; r < 4; ++r) {
            s[r] += __shfl_xor(s[r], m, 64);
            q[r] += __shfl_xor(q[r], m, 64);
        }

    #pragma unroll
    for (int r = 0; r < 4; ++r) {
        const float mu   = s[r] * (1.0f / 128.0f);
        const float var  = q[r] * (1.0f / 128.0f) - mu * mu;
        const float rstd = rsqrtf(var + LN_EPS);
        const int row = wrow0 + kq * 4 + r;
        const int ge  = e0g + row;
        const int dn  = edge_index[NEDGES + ge];
        const size_t erow = (size_t)ge * D;
        float* ap = agg + (size_t)dn * D;
        #pragma unroll
        for (int nf = 0; nf < 8; ++nf) {
            const int col = nf * 16 + c16;
            float o = (acc2[nf][r] - mu) * rstd * gv[nf] + bvv[nf];
            edges_out[erow + col] = o;
            atomicAdd(ap + col, o);
        }
    }
}

// ---------------------------------------------------------------------------
// Fallback edge kernel (round-6 structure) when ws is too small for precompute
// ---------------------------------------------------------------------------
__global__ __launch_bounds__(BLK, 4) void edge_kernel_fb(
    const float* __restrict__ x,
    const float* __restrict__ edge_attr,
    const int*   __restrict__ edge_index,
    const __bf16* __restrict__ W1f,
    const float* __restrict__ b1,
    const __bf16* __restrict__ W2f,
    const float* __restrict__ b2,
    const float* __restrict__ lng, const float* __restrict__ lnb,
    float* __restrict__ edges_out,
    float* __restrict__ agg)
{
    __shared__ __bf16 in_t[TE][264];
    __shared__ int    src_s[TE], dst_s[TE];

    const int tid = threadIdx.x;
    const int e0g = blockIdx.x * TE;

    if (tid < TE) {
        src_s[tid] = edge_index[e0g + tid];
        dst_s[tid] = edge_index[NEDGES + e0g + tid];
    }
    __syncthreads();

    const int lane  = tid & 63;
    const int wid   = tid >> 6;
    const int wrow0 = wid << 4;
    const int c16   = lane & 15;
    const int kq    = lane >> 4;
    const int ks8   = kq << 3;
    const int lo8   = lane << 3;

    bf16x8 aE[4];
    {
        const float* ep = edge_attr + (size_t)(e0g + wrow0 + c16) * D + ks8;
        #pragma unroll
        for (int ks2 = 0; ks2 < 4; ++ks2) {
            fx4 v0 = *(const fx4*)(ep + (ks2 << 5));
            fx4 v1 = *(const fx4*)(ep + (ks2 << 5) + 4);
            bf16x8 a;
            #pragma unroll
            for (int j = 0; j < 4; ++j) { a[j] = (__bf16)v0[j]; a[j + 4] = (__bf16)v1[j]; }
            aE[ks2] = a;
        }
    }

    #pragma unroll
    for (int it = 0; it < 8; ++it) {
        const int idx = tid + it * BLK;
        const int e   = idx >> 5;
        const int c4  = (idx & 31) << 2;
        fx4 v = *(const fx4*)&x[(size_t)dst_s[e] * D + c4];
        bf16x4 h;
        #pragma unroll
        for (int j = 0; j < 4; ++j) h[j] = (__bf16)v[j];
        *(bf16x4*)&in_t[e][c4] = h;
    }
    #pragma unroll
    for (int it = 0; it < 8; ++it) {
        const int idx = tid + it * BLK;
        const int e   = idx >> 5;
        const int c4  = (idx & 31) << 2;
        fx4 v = *(const fx4*)&x[(size_t)src_s[e] * D + c4];
        bf16x4 h;
        #pragma unroll
        for (int j = 0; j < 4; ++j) h[j] = (__bf16)v[j];
        *(bf16x4*)&in_t[e][128 + c4] = h;
    }
    __syncthreads();

    f32x4 acc[8];
    #pragma unroll
    for (int nf = 0; nf < 8; ++nf) acc[nf] = (f32x4){0.f, 0.f, 0.f, 0.f};

    #pragma unroll
    for (int ks = 0; ks < 12; ++ks) {
        bf16x8 a = (ks < 8) ? *(const bf16x8*)&in_t[wrow0 + c16][(ks << 5) + ks8]
                            : aE[ks - 8];
        const __bf16* wp = W1f + ((size_t)(ks << 3) << 9) + lo8;
        #pragma unroll
        for (int nf = 0; nf < 8; ++nf) {
            bf16x8 b = *(const bf16x8*)(wp + (nf << 9));
            acc[nf] = __builtin_amdgcn_mfma_f32_16x16x32_bf16(a, b, acc[nf], 0, 0, 0);
        }
    }

    #pragma unroll
    for (int nf = 0; nf < 8; ++nf) {
        const float bb = b1[nf * 16 + c16];
        #pragma unroll
        for (int r = 0; r < 4; ++r) {
            float h = silu_f(acc[nf][r] + bb);
            in_t[wrow0 + kq * 4 + r][nf * 16 + c16] = (__bf16)h;
        }
    }

    f32x4 acc2[8];
    #pragma unroll
    for (int nf = 0; nf < 8; ++nf) acc2[nf] = (f32x4){0.f, 0.f, 0.f, 0.f};

    #pragma unroll
    for (int ks = 0; ks < 4; ++ks) {
        bf16x8 a = *(const bf16x8*)&in_t[wrow0 + c16][(ks << 5) + ks8];
        const __bf16* wp = W2f + ((size_t)(ks << 3) << 9) + lo8;
        #pragma unroll
        for (int nf = 0; nf < 8; ++nf) {
            bf16x8 b = *(const bf16x8*)(wp + (nf << 9));
            acc2[nf] = __builtin_amdgcn_mfma_f32_16x16x32_bf16(a, b, acc2[nf], 0, 0, 0);
        }
    }

    float b2v[8], gv[8], bvv[8];
    #pragma unroll
    for (int nf = 0; nf < 8; ++nf) {
        b2v[nf] = b2[nf * 16 + c16];
        gv[nf]  = lng[nf * 16 + c16];
        bvv[nf] = lnb[nf * 16 + c16];
    }

    float s[4] = {0.f, 0.f, 0.f, 0.f}, q[4] = {0.f, 0.f, 0.f, 0.f};
    #pragma unroll
    for (int nf = 0; nf < 8; ++nf)
        #pragma unroll
        for (int r = 0; r < 4; ++r) {
            float zz = acc2[nf][r] + b2v[nf];
            acc2[nf][r] = zz;
            s[r] += zz;
            q[r] += zz * zz;
        }
    #pragma unroll
    for (int m = 1; m <= 8; m <<= 1)
        #pragma unroll
        for (int r = 0; r < 4; ++r) {
            s[r] += __shfl_xor(s[r], m, 64);
            q[r] += __shfl_xor(q[r], m, 64);
        }

    #pragma unroll
    for (int r = 0; r < 4; ++r) {
        const float mu   = s[r] * (1.0f / 128.0f);
        const float var  = q[r] * (1.0f / 128.0f) - mu * mu;
        const float rstd = rsqrtf(var + LN_EPS);
        const int row = wrow0 + kq * 4 + r;
        const size_t erow = (size_t)(e0g + row) * D;
        float* ap = agg + (size_t)dst_s[row] * D;
        #pragma unroll
        for (int nf = 0; nf < 8; ++nf) {
            const int col = nf * 16 + c16;
            float o = (acc2[nf][r] - mu) * rstd * gv[nf] + bvv[nf];
            edges_out[erow + col] = o;
            atomicAdd(ap + col, o);
        }
    }
}

// ---------------------------------------------------------------------------
// Node kernel (bf16 MFMA): 64 nodes/block; in = [x, agg] (256)
// ---------------------------------------------------------------------------
__global__ __launch_bounds__(BLK, 4) void node_kernel(
    const float* __restrict__ x,
    const float* __restrict__ agg,
    const __bf16* __restrict__ W1f,
    const float* __restrict__ b1,
    const __bf16* __restrict__ W2f,
    const float* __restrict__ b2,
    const float* __restrict__ lng, const float* __restrict__ lnb,
    float* __restrict__ nodes_out)
{
    __shared__ __bf16 in_t[TN][264];

    const int tid = threadIdx.x;
    const int r0g = blockIdx.x * TN;

    #pragma unroll
    for (int it = 0; it < 8; ++it) {
        const int idx = tid + it * BLK;
        const int e   = idx >> 5;
        const int c4  = (idx & 31) << 2;
        const int row = r0g + e;
        fx4 v = {0.f, 0.f, 0.f, 0.f};
        if (row < NNODES) v = *(const fx4*)&x[(size_t)row * D + c4];
        bf16x4 h;
        #pragma unroll
        for (int j = 0; j < 4; ++j) h[j] = (__bf16)v[j];
        *(bf16x4*)&in_t[e][c4] = h;
    }
    #pragma unroll
    for (int it = 0; it < 8; ++it) {
        const int idx = tid + it * BLK;
        const int e   = idx >> 5;
        const int c4  = (idx & 31) << 2;
        const int row = r0g + e;
        fx4 v = {0.f, 0.f, 0.f, 0.f};
        if (row < NNODES) v = *(const fx4*)&agg[(size_t)row * D + c4];
        bf16x4 h;
        #pragma unroll
        for (int j = 0; j < 4; ++j) h[j] = (__bf16)v[j];
        *(bf16x4*)&in_t[e][128 + c4] = h;
    }
    __syncthreads();

    const int lane  = tid & 63;
    const int wid   = tid >> 6;
    const int wrow0 = wid << 4;
    const int c16   = lane & 15;
    const int kq    = lane >> 4;
    const int ks8   = kq << 3;
    const int lo8   = lane << 3;

    f32x4 acc[8];
    #pragma unroll
    for (int nf = 0; nf < 8; ++nf) acc[nf] = (f32x4){0.f, 0.f, 0.f, 0.f};

    #pragma unroll
    for (int ks = 0; ks < 8; ++ks) {
        bf16x8 a = *(const bf16x8*)&in_t[wrow0 + c16][(ks << 5) + ks8];
        const __bf16* wp = W1f + ((size_t)(ks << 3) << 9) + lo8;
        #pragma unroll
        for (int nf = 0; nf < 8; ++nf) {
            bf16x8 b = *(const bf16x8*)(wp + (nf << 9));
            acc[nf] = __builtin_amdgcn_mfma_f32_16x16x32_bf16(a, b, acc[nf], 0, 0, 0);
        }
    }

    #pragma unroll
    for (int nf = 0; nf < 8; ++nf) {
        const float bb = b1[nf * 16 + c16];
        #pragma unroll
        for (int r = 0; r < 4; ++r) {
            float h = silu_f(acc[nf][r] + bb);
            in_t[wrow0 + kq * 4 + r][nf * 16 + c16] = (__bf16)h;
        }
    }

    f32x4 acc2[8];
    #pragma unroll
    for (int nf = 0; nf < 8; ++nf) acc2[nf] = (f32x4){0.f, 0.f, 0.f, 0.f};

    #pragma unroll
    for (int ks = 0; ks < 4; ++ks) {
        bf16x8 a = *(const bf16x8*)&in_t[wrow0 + c16][(ks << 5) + ks8];
        const __bf16* wp = W2f + ((size_t)(ks << 3) << 9) + lo8;
        #pragma unroll
        for (int nf = 0; nf < 8; ++nf) {
            bf16x8 b = *(const bf16x8*)(wp + (nf << 9));
            acc2[nf] = __builtin_amdgcn_mfma_f32_16x16x32_bf16(a, b, acc2[nf], 0, 0, 0);
        }
    }

    float b2v[8], gv[8], bvv[8];
    #pragma unroll
    for (int nf = 0; nf < 8; ++nf) {
        b2v[nf] = b2[nf * 16 + c16];
        gv[nf]  = lng[nf * 16 + c16];
        bvv[nf] = lnb[nf * 16 + c16];
    }

    float s[4] = {0.f, 0.f, 0.f, 0.f}, q[4] = {0.f, 0.f, 0.f, 0.f};
    #pragma unroll
    for (int nf = 0; nf < 8; ++nf)
        #pragma unroll
        for (int r = 0; r < 4; ++r) {
            float zz = acc2[nf][r] + b2v[nf];
            acc2[nf][r] = zz;
            s[r] += zz;
            q[r] += zz * zz;
        }
    #pragma unroll
    for (int m = 1; m <= 8; m <<= 1)
        #pragma unroll
        for (int r = 0; r < 4; ++r) {
            s[r] += __shfl_xor(s[r], m, 64);
            q[r] += __shfl_xor(q[r], m, 64);
        }

    #pragma unroll
    for (int r = 0; r < 4; ++r) {
        const float mu   = s[r] * (1.0f / 128.0f);
        const float var  = q[r] * (1.0f / 128.0f) - mu * mu;
        const float rstd = rsqrtf(var + LN_EPS);
        const int row = r0g + wrow0 + kq * 4 + r;
        if (row >= NNODES) continue;
        const size_t orow = (size_t)row * D;
        #pragma unroll
        for (int nf = 0; nf < 8; ++nf) {
            const int col = nf * 16 + c16;
            float o = (acc2[nf][r] - mu) * rstd * gv[nf] + bvv[nf] + x[orow + col];
            nodes_out[orow + col] = o;
        }
    }
}

extern "C" void kernel_launch(void* const* d_in, const int* in_sizes, int n_in,
                              void* d_out, int out_size, void* d_ws, size_t ws_size,
                              hipStream_t stream) {
    (void)in_sizes; (void)n_in; (void)out_size;

    const float* x         = (const float*)d_in[0];
    const float* edge_attr = (const float*)d_in[1];
    const int*   edge_idx  = (const int*)  d_in[2];
    const float* eW1 = (const float*)d_in[3];
    const float* eb1 = (const float*)d_in[4];
    const float* eW2 = (const float*)d_in[5];
    const float* eb2 = (const float*)d_in[6];
    const float* elg = (const float*)d_in[7];
    const float* elb = (const float*)d_in[8];
    const float* nW1 = (const float*)d_in[9];
    const float* nb1 = (const float*)d_in[10];
    const float* nW2 = (const float*)d_in[11];
    const float* nb2 = (const float*)d_in[12];
    const float* nlg = (const float*)d_in[13];
    const float* nlb = (const float*)d_in[14];

    float* out       = (float*)d_out;
    float* nodes_out = out;                        // doubles as agg accumulator
    float* edges_out = out + (size_t)NNODES * D;

    char*   wsb = (char*)d_ws;
    __bf16* ws  = (__bf16*)d_ws;

    prep_weights<<<(WS_ELEMS + 255) / 256, 256, 0, stream>>>(eW1, eW2, nW1, nW2, ws);

    hipMemsetAsync(nodes_out, 0, (size_t)NNODES * D * sizeof(float), stream);

    if (ws_size >= WS_NEED_PRE) {
        float* Pd = (float*)(wsb + PD_OFF);
        float* Ps = (float*)(wsb + PS_OFF);

        pre_nodes<<<(NNODES + TN - 1) / TN, BLK, 0, stream>>>(
            x, ws + EW1F_OFF, eb1, Pd, Ps);

        edge_kernel_pre<<<NEDGES / TE, BLK, 0, stream>>>(
            edge_attr, edge_idx, Pd, Ps,
            ws + EW1F_OFF, ws + EW2F_OFF, eb2, elg, elb,
            edges_out, nodes_out);
    } else {
        edge_kernel_fb<<<NEDGES / TE, BLK, 0, stream>>>(
            x, edge_attr, edge_idx,
            ws + EW1F_OFF, eb1, ws + EW2F_OFF, eb2, elg, elb,
            edges_out, nodes_out);
    }

    node_kernel<<<(NNODES + TN - 1) / TN, BLK, 0, stream>>>(
        x, nodes_out,
        ws + NW1F_OFF, nb1, ws + NW2F_OFF, nb2, nlg, nlb,
        nodes_out);
}